// Round 3
// baseline (1460.757 us; speedup 1.0000x reference)
//
#include <hip/hip_runtime.h>
#include <hip/hip_cooperative_groups.h>
#include <hip/hip_bf16.h>
#include <stdint.h>

typedef __hip_bfloat16 bf16;
typedef __hip_bfloat162 bf162;

typedef __attribute__((ext_vector_type(8))) short short8;   // 8 bf16 = 4 VGPRs
typedef __attribute__((ext_vector_type(4))) float floatx4;  // MFMA accumulator

#define BSH   8        // bucket = 256 nodes (fallback path)
#define BSZ   256
#define CHUNK 8192     // edges per sort block (fallback path)
#define NBMAX 512      // max buckets supported (N <= 131072)

// ---------------- helpers ----------------

__device__ __forceinline__ void acc2(float& a, float& b, unsigned u) {
    a += __uint_as_float(u << 16);
    b += __uint_as_float(u & 0xffff0000u);
}

// ==================================================================
// ===============  cooperative mega-kernel path  ===================
// ==================================================================
// One dispatch for the whole pipeline. Phases separated by grid.sync():
//  P0: zero deg | cvt x->bf16 | weight swizzle (independent, one phase)
//  P1: degree histogram (global atomics)
//  P2-P4: exclusive scan deg->rp (block partials, block-0 scan, add+cursor)
//  P5: scatter edges into CSR col (atomic cursors; order within a node is
//      irrelevant -- aggregation is a sum)
//  P6..: 3 x { agg phase ; sync ; dual-GEMM phase ; sync }
// Replaces 16 dispatches (and their launch gaps) with 1 + 11 grid syncs.

struct MegaArgs {
    const float* x;
    const int*   ei;
    const float *wr1, *wo1, *wr2, *wo2, *wr3, *wo3;
    const float *b1, *b2, *b3;
    float* out;
    bf16 *xbf, *h1, *aggb;
    bf16 *wsw1, *wsw2, *wsw3;
    int  *col, *rp, *cur, *deg, *Pb;
    int N, E;
};

__global__ __launch_bounds__(256)
void mega_kernel(MegaArgs a) {
    namespace cg = cooperative_groups;
    cg::grid_group grid = cg::this_grid();

    __shared__ int sscan[256];

    const int tid  = threadIdx.x;
    const int gtid = blockIdx.x * blockDim.x + tid;
    const int gsz  = gridDim.x * blockDim.x;
    const int N = a.N, E = a.E;
    const int* src = a.ei;
    const int* dst = a.ei + E;

    // ---- P0: zero deg + cvt + weight swizzle ----
    {
        for (int i = gtid; i < N; i += gsz) a.deg[i] = 0;
        const int n4 = N * 32;
        for (int i = gtid; i < n4; i += gsz) {
            float4 v = ((const float4*)a.x)[i];
            bf162 p, q;
            p.x = __float2bfloat16(v.x); p.y = __float2bfloat16(v.y);
            q.x = __float2bfloat16(v.z); q.y = __float2bfloat16(v.w);
            ((bf162*)a.xbf)[i * 2]     = p;
            ((bf162*)a.xbf)[i * 2 + 1] = q;
        }
        for (int t = gtid; t < 3 * 4096; t += gsz) {
            const int layer = t >> 12;
            const int u = t & 4095;
            const float* wrel  = (layer == 0) ? a.wr1 : (layer == 1) ? a.wr2 : a.wr3;
            const float* wroot = (layer == 0) ? a.wo1 : (layer == 1) ? a.wo2 : a.wo3;
            bf16*        wsw   = (layer == 0) ? a.wsw1 : (layer == 1) ? a.wsw2 : a.wsw3;
            const int lane = u & 63;
            const int ct   = (u >> 6) & 7;
            const int kt   = u >> 9;
            const int kbase = kt * 32 + (lane >> 4) * 8;
            const int n     = ct * 16 + (lane & 15);
            bf16* q = wsw + (size_t)u * 8;
#pragma unroll
            for (int j = 0; j < 8; ++j) {
                const int k = kbase + j;
                const float v = (k < 128) ? wrel[k * 128 + n] : wroot[(k - 128) * 128 + n];
                q[j] = __float2bfloat16(v);
            }
        }
    }
    grid.sync();

    // ---- P1: degree histogram ----
    for (int e = gtid; e < E; e += gsz)
        atomicAdd(&a.deg[dst[e]], 1);
    grid.sync();

    // ---- P2: per-block chunk scan of deg -> rp (local), partial to Pb ----
    const int C = (N + gridDim.x - 1) / gridDim.x;
    {
        const int base = blockIdx.x * C;
        int carry = 0;
        for (int off = 0; off < C; off += 256) {
            const int idx = base + off + tid;
            const bool ok = (off + tid < C) && (idx < N);
            const int v = ok ? a.deg[idx] : 0;
            sscan[tid] = v;
            __syncthreads();
            for (int d = 1; d < 256; d <<= 1) {
                int u = (tid >= d) ? sscan[tid - d] : 0;
                __syncthreads();
                sscan[tid] += u;
                __syncthreads();
            }
            if (ok) a.rp[idx] = carry + sscan[tid] - v;
            const int tot = sscan[255];
            __syncthreads();
            carry += tot;
        }
        if (tid == 0) a.Pb[blockIdx.x] = carry;
    }
    grid.sync();

    // ---- P3: block 0 exclusive-scans the partials ----
    if (blockIdx.x == 0) {
        const int G = gridDim.x;
        int carry = 0;
        for (int off = 0; off < G; off += 256) {
            const int i = off + tid;
            const int v = (i < G) ? a.Pb[i] : 0;
            sscan[tid] = v;
            __syncthreads();
            for (int d = 1; d < 256; d <<= 1) {
                int u = (tid >= d) ? sscan[tid - d] : 0;
                __syncthreads();
                sscan[tid] += u;
                __syncthreads();
            }
            if (i < G) a.Pb[i] = carry + sscan[tid] - v;
            const int tot = sscan[255];
            __syncthreads();
            carry += tot;
        }
    }
    grid.sync();

    // ---- P4: add block offsets, build cursors, rp[N] = E ----
    {
        const int base = blockIdx.x * C;
        const int o = a.Pb[blockIdx.x];
        for (int off = tid; off < C; off += 256) {
            const int idx = base + off;
            if (idx < N) {
                const int r = a.rp[idx] + o;
                a.rp[idx]  = r;
                a.cur[idx] = r;
            }
        }
        if (gtid == 0) a.rp[N] = E;
    }
    grid.sync();

    // ---- P5: scatter edges into CSR col ----
    for (int e = gtid; e < E; e += gsz) {
        const int d = dst[e];
        const int p = atomicAdd(&a.cur[d], 1);
        a.col[p] = src[e];
    }
    grid.sync();

    // ---- P6..: layers ----
    const int lane = tid & 63;
    const int wid  = tid >> 6;
    const int nwaves = gsz >> 6;
    const int half = lane >> 5;
    const int l32  = lane & 31;
    const int f    = l32 * 4;
    const int l15  = lane & 15;
    const int quad = lane >> 4;
    const int tiles = (N + 63) >> 6;

    for (int L = 0; L < 3; ++L) {
        const bf16* Hin = (L == 0) ? a.xbf : (L == 1) ? a.h1 : a.xbf;  // h2 aliases xbf
        bf16*  houtb = (L == 0) ? a.h1 : a.xbf;
        const bf16* wsw = (L == 0) ? a.wsw1 : (L == 1) ? a.wsw2 : a.wsw3;
        const float* bias = (L == 0) ? a.b1 : (L == 1) ? a.b2 : a.b3;

        // ---- agg phase: one wave per node, grid-stride ----
        for (int node = blockIdx.x * 4 + wid; node < N; node += nwaves) {
            const int beg = a.rp[node], end = a.rp[node + 1];
            float acc[4] = {0.f, 0.f, 0.f, 0.f};
            int e = beg;
#pragma unroll 2
            for (; e + 8 <= end; e += 8) {
                const int s0 = a.col[e + half];
                const int s1 = a.col[e + 2 + half];
                const int s2 = a.col[e + 4 + half];
                const int s3 = a.col[e + 6 + half];
                const uint2 r0 = *(const uint2*)(Hin + (size_t)s0 * 128 + f);
                const uint2 r1 = *(const uint2*)(Hin + (size_t)s1 * 128 + f);
                const uint2 r2 = *(const uint2*)(Hin + (size_t)s2 * 128 + f);
                const uint2 r3 = *(const uint2*)(Hin + (size_t)s3 * 128 + f);
                acc2(acc[0], acc[1], r0.x); acc2(acc[2], acc[3], r0.y);
                acc2(acc[0], acc[1], r1.x); acc2(acc[2], acc[3], r1.y);
                acc2(acc[0], acc[1], r2.x); acc2(acc[2], acc[3], r2.y);
                acc2(acc[0], acc[1], r3.x); acc2(acc[2], acc[3], r3.y);
            }
            for (; e < end; e += 2) {
                const bool act = (e + half) < end;
                const int s = a.col[act ? (e + half) : e];
                const uint2 r = *(const uint2*)(Hin + (size_t)s * 128 + f);
                if (act) { acc2(acc[0], acc[1], r.x); acc2(acc[2], acc[3], r.y); }
            }
#pragma unroll
            for (int j = 0; j < 4; ++j)
                acc[j] += __shfl_xor(acc[j], 32, 64);
            if (half == 0) {
                bf162 o0, o1;
                o0.x = __float2bfloat16(acc[0]); o0.y = __float2bfloat16(acc[1]);
                o1.x = __float2bfloat16(acc[2]); o1.y = __float2bfloat16(acc[3]);
                bf162* q = (bf162*)(a.aggb + (size_t)node * 128 + f);
                q[0] = o0;
                q[1] = o1;
            }
        }
        grid.sync();

        // ---- dual-GEMM phase: out = [agg|Hin] @ Wsw + b (+relu), grid-stride tiles ----
        for (int tb = blockIdx.x; tb < tiles; tb += gridDim.x) {
            const int row_a = tb * 64 + wid * 16 + l15;
            const bool rowok = row_a < N;
            floatx4 acc[8];
#pragma unroll
            for (int ct = 0; ct < 8; ++ct) acc[ct] = (floatx4){0.f, 0.f, 0.f, 0.f};
#pragma unroll
            for (int kt = 0; kt < 8; ++kt) {
                const bf16* Abase = (kt < 4) ? a.aggb : Hin;
                const int k0 = (kt & 3) * 32 + quad * 8;
                short8 afrag = (short8){0, 0, 0, 0, 0, 0, 0, 0};
                if (rowok) afrag = *(const short8*)(Abase + (size_t)row_a * 128 + k0);
#pragma unroll
                for (int ct = 0; ct < 8; ++ct) {
                    const short8 bfrag = *(const short8*)(wsw + (size_t)((kt * 8 + ct) * 64 + lane) * 8);
                    acc[ct] = __builtin_amdgcn_mfma_f32_16x16x32_bf16(afrag, bfrag, acc[ct], 0, 0, 0);
                }
            }
            const int row_o = tb * 64 + wid * 16 + quad * 4;
#pragma unroll
            for (int ct = 0; ct < 8; ++ct) {
                const int colc = ct * 16 + l15;
                const float bv = bias[colc];
#pragma unroll
                for (int r = 0; r < 4; ++r) {
                    const int row = row_o + r;
                    if (row < N) {
                        float v = acc[ct][r] + bv;
                        if (L < 2) {
                            v = fmaxf(v, 0.f);
                            houtb[(size_t)row * 128 + colc] = __float2bfloat16(v);
                        } else {
                            a.out[(size_t)row * 128 + colc] = v;
                        }
                    }
                }
            }
        }
        if (L < 2) grid.sync();
    }
}

// ==================================================================
// ===============  fallback multi-kernel path  =====================
// ==================================================================

__global__ __launch_bounds__(256)
void prep_kernel(const float* __restrict__ x, bf16* __restrict__ y, int n4, int nCvt,
                 const float* __restrict__ wr1, const float* __restrict__ wo1,
                 const float* __restrict__ wr2, const float* __restrict__ wo2,
                 const float* __restrict__ wr3, const float* __restrict__ wo3,
                 bf16* __restrict__ w1, bf16* __restrict__ w2, bf16* __restrict__ w3) {
    const int b = blockIdx.x;
    if (b < nCvt) {
        const int i = b * 256 + threadIdx.x;
        if (i < n4) {
            float4 v = ((const float4*)x)[i];
            bf162 a, c;
            a.x = __float2bfloat16(v.x); a.y = __float2bfloat16(v.y);
            c.x = __float2bfloat16(v.z); c.y = __float2bfloat16(v.w);
            ((bf162*)y)[i * 2]     = a;
            ((bf162*)y)[i * 2 + 1] = c;
        }
        return;
    }
    int t = (b - nCvt) * 256 + threadIdx.x;
    const int layer = t >> 12;
    t &= 4095;
    const float* wrel  = (layer == 0) ? wr1 : (layer == 1) ? wr2 : wr3;
    const float* wroot = (layer == 0) ? wo1 : (layer == 1) ? wo2 : wo3;
    bf16*        wsw   = (layer == 0) ? w1  : (layer == 1) ? w2  : w3;
    const int lane = t & 63;
    const int ct   = (t >> 6) & 7;
    const int kt   = t >> 9;
    const int kbase = kt * 32 + (lane >> 4) * 8;
    const int n     = ct * 16 + (lane & 15);
    bf16* q = wsw + (size_t)t * 8;
#pragma unroll
    for (int j = 0; j < 8; ++j) {
        const int k = kbase + j;
        const float v = (k < 128) ? wrel[k * 128 + n] : wroot[(k - 128) * 128 + n];
        q[j] = __float2bfloat16(v);
    }
}

__global__ __launch_bounds__(256)
void bhist_kernel(const int* __restrict__ dst, int* __restrict__ T,
                  int E, int NB, int GB) {
    __shared__ int lh[NBMAX];
    const int b = blockIdx.x;
    for (int u = threadIdx.x; u < NB; u += 256) lh[u] = 0;
    __syncthreads();
    const int beg = b * CHUNK, end = min(beg + CHUNK, E);
    for (int e = beg + threadIdx.x; e < end; e += 256)
        atomicAdd(&lh[dst[e] >> BSH], 1);
    __syncthreads();
    for (int u = threadIdx.x; u < NB; u += 256)
        T[u * GB + b] = lh[u];
}

__global__ __launch_bounds__(256)
void scan1_kernel(const int* __restrict__ deg, int* __restrict__ rp,
                  int* __restrict__ bsum, int n) {
    __shared__ int s[256];
    const int tid = threadIdx.x;
    const int i = blockIdx.x * 256 + tid;
    const int d = (i < n) ? deg[i] : 0;
    s[tid] = d;
    __syncthreads();
    for (int off = 1; off < 256; off <<= 1) {
        int u = (tid >= off) ? s[tid - off] : 0;
        __syncthreads();
        s[tid] += u;
        __syncthreads();
    }
    if (i < n) rp[i] = s[tid] - d;
    if (tid == 255) bsum[blockIdx.x] = s[255];
}

__global__ __launch_bounds__(512)
void scan2_kernel(int* __restrict__ bsum, int G) {
    __shared__ int s[512];
    const int tid = threadIdx.x;
    const int d = (tid < G) ? bsum[tid] : 0;
    s[tid] = d;
    __syncthreads();
    for (int off = 1; off < 512; off <<= 1) {
        int u = (tid >= off) ? s[tid - off] : 0;
        __syncthreads();
        s[tid] += u;
        __syncthreads();
    }
    if (tid < G) bsum[tid] = s[tid] - d;
}

__global__ __launch_bounds__(256)
void scan3_kernel(int* __restrict__ rp, const int* __restrict__ bsum, int n) {
    const int i = blockIdx.x * 256 + threadIdx.x;
    if (i < n) rp[i] += bsum[blockIdx.x];
}

__global__ __launch_bounds__(256)
void bscatter_kernel(const int* __restrict__ src, const int* __restrict__ dst,
                     const int* __restrict__ T, int* __restrict__ ebuf,
                     int E, int NB, int GB) {
    __shared__ int lofs[NBMAX];
    const int b = blockIdx.x;
    for (int u = threadIdx.x; u < NB; u += 256)
        lofs[u] = T[u * GB + b];
    __syncthreads();
    const int beg = b * CHUNK, end = min(beg + CHUNK, E);
    for (int e = beg + threadIdx.x; e < end; e += 256) {
        const int d = dst[e];
        const int u = d >> BSH;
        const int pos = atomicAdd(&lofs[u], 1);
        ebuf[pos] = (src[e] << BSH) | (d & (BSZ - 1));
    }
}

__global__ __launch_bounds__(256)
void bbuild_kernel(const int* __restrict__ T, const int* __restrict__ ebuf,
                   int* __restrict__ rp, int* __restrict__ col,
                   int E, int N, int NB, int GB) {
    __shared__ int s[256];
    __shared__ int lrank[256];
    const int u = blockIdx.x;
    const int tid = threadIdx.x;
    const int beg = T[u * GB];
    const int end = (u + 1 < NB) ? T[(u + 1) * GB] : E;

    lrank[tid] = 0;
    __syncthreads();
    for (int e = beg + tid; e < end; e += 256)
        atomicAdd(&lrank[ebuf[e] & (BSZ - 1)], 1);
    __syncthreads();
    const int cntv = lrank[tid];
    s[tid] = cntv;
    __syncthreads();
    for (int off = 1; off < 256; off <<= 1) {
        int v = (tid >= off) ? s[tid - off] : 0;
        __syncthreads();
        s[tid] += v;
        __syncthreads();
    }
    const int excl = s[tid] - cntv;
    const int node = u * BSZ + tid;
    if (node < N) rp[node] = beg + excl;
    if (u == NB - 1 && tid == 0) rp[N] = E;
    lrank[tid] = beg + excl;
    __syncthreads();
    for (int e = beg + tid; e < end; e += 256) {
        const int p = ebuf[e];
        const int pos = atomicAdd(&lrank[p & (BSZ - 1)], 1);
        col[pos] = p >> BSH;
    }
}

__global__ __launch_bounds__(512)
void agg_kernel(const bf16* __restrict__ h, const int* __restrict__ rp,
                const int* __restrict__ col, bf16* __restrict__ agg, int N) {
    const int lane = threadIdx.x & 63;
    const int wid  = threadIdx.x >> 6;
    const int node = blockIdx.x * 8 + wid;
    if (node >= N) return;
    const int half = lane >> 5;
    const int l32  = lane & 31;
    const int f    = l32 * 4;
    const int beg = rp[node], end = rp[node + 1];

    float acc[4] = {0.f, 0.f, 0.f, 0.f};
    int e = beg;
#pragma unroll 2
    for (; e + 8 <= end; e += 8) {
        const int s0 = col[e + half];
        const int s1 = col[e + 2 + half];
        const int s2 = col[e + 4 + half];
        const int s3 = col[e + 6 + half];
        const uint2 r0 = *(const uint2*)(h + (size_t)s0 * 128 + f);
        const uint2 r1 = *(const uint2*)(h + (size_t)s1 * 128 + f);
        const uint2 r2 = *(const uint2*)(h + (size_t)s2 * 128 + f);
        const uint2 r3 = *(const uint2*)(h + (size_t)s3 * 128 + f);
        acc2(acc[0], acc[1], r0.x); acc2(acc[2], acc[3], r0.y);
        acc2(acc[0], acc[1], r1.x); acc2(acc[2], acc[3], r1.y);
        acc2(acc[0], acc[1], r2.x); acc2(acc[2], acc[3], r2.y);
        acc2(acc[0], acc[1], r3.x); acc2(acc[2], acc[3], r3.y);
    }
    for (; e < end; e += 2) {
        const bool act = (e + half) < end;
        const int s = col[act ? (e + half) : e];
        const uint2 r = *(const uint2*)(h + (size_t)s * 128 + f);
        if (act) { acc2(acc[0], acc[1], r.x); acc2(acc[2], acc[3], r.y); }
    }
#pragma unroll
    for (int j = 0; j < 4; ++j)
        acc[j] += __shfl_xor(acc[j], 32, 64);
    if (half == 0) {
        bf162 o0, o1;
        o0.x = __float2bfloat16(acc[0]); o0.y = __float2bfloat16(acc[1]);
        o1.x = __float2bfloat16(acc[2]); o1.y = __float2bfloat16(acc[3]);
        bf162* q = (bf162*)(agg + (size_t)node * 128 + f);
        q[0] = o0;
        q[1] = o1;
    }
}

template <bool RELU, typename OT>
__global__ __launch_bounds__(256)
void mfma_gemm_kernel(const bf16* __restrict__ Aagg, const bf16* __restrict__ Hroot,
                      const bf16* __restrict__ wsw, const float* __restrict__ bias,
                      OT* __restrict__ out, int M) {
    const int tid  = threadIdx.x;
    const int lane = tid & 63;
    const int wave = tid >> 6;
    const int l15  = lane & 15;
    const int quad = lane >> 4;

    const int row_a = blockIdx.x * 64 + wave * 16 + l15;
    const bool rowok = row_a < M;

    floatx4 acc[8];
#pragma unroll
    for (int ct = 0; ct < 8; ++ct) acc[ct] = (floatx4){0.f, 0.f, 0.f, 0.f};

#pragma unroll
    for (int kt = 0; kt < 8; ++kt) {
        const bf16* Abase = (kt < 4) ? Aagg : Hroot;
        const int k0 = (kt & 3) * 32 + quad * 8;
        short8 afrag = (short8){0, 0, 0, 0, 0, 0, 0, 0};
        if (rowok) afrag = *(const short8*)(Abase + (size_t)row_a * 128 + k0);
#pragma unroll
        for (int ct = 0; ct < 8; ++ct) {
            const short8 bfrag = *(const short8*)(wsw + (size_t)((kt * 8 + ct) * 64 + lane) * 8);
            acc[ct] = __builtin_amdgcn_mfma_f32_16x16x32_bf16(afrag, bfrag, acc[ct], 0, 0, 0);
        }
    }

    const int row_o = blockIdx.x * 64 + wave * 16 + quad * 4;
#pragma unroll
    for (int ct = 0; ct < 8; ++ct) {
        const int colc = ct * 16 + l15;
        const float bv = bias[colc];
#pragma unroll
        for (int r = 0; r < 4; ++r) {
            const int row = row_o + r;
            if (row < M) {
                float v = acc[ct][r] + bv;
                if (RELU) v = fmaxf(v, 0.f);
                if constexpr (sizeof(OT) == 2)
                    ((bf16*)out)[(size_t)row * 128 + colc] = __float2bfloat16(v);
                else
                    ((float*)out)[(size_t)row * 128 + colc] = v;
            }
        }
    }
}

// ---------------- launch ----------------

extern "C" void kernel_launch(void* const* d_in, const int* in_sizes, int n_in,
                              void* d_out, int out_size, void* d_ws, size_t ws_size,
                              hipStream_t stream) {
    const float* x       = (const float*)d_in[0];
    const int*   ei      = (const int*)d_in[1];
    const float* w_rel1  = (const float*)d_in[2];
    const float* w_root1 = (const float*)d_in[3];
    const float* b1      = (const float*)d_in[4];
    const float* w_rel2  = (const float*)d_in[5];
    const float* w_root2 = (const float*)d_in[6];
    const float* b2      = (const float*)d_in[7];
    const float* w_rel3  = (const float*)d_in[8];
    const float* w_root3 = (const float*)d_in[9];
    const float* b3      = (const float*)d_in[10];
    float* out = (float*)d_out;

    const int N = in_sizes[0] / 128;
    const int E = in_sizes[1] / 2;
    const int* src = ei;
    const int* dst = ei + E;

    // workspace layout (~85 MB)
    char* w = (char*)d_ws;
    auto alloc = [&](size_t bytes) {
        char* p = w;
        w += (bytes + 255) & ~(size_t)255;
        return p;
    };
    int*  col  = (int*)alloc((size_t)E * 4);            // 6.4 MB
    int*  rp   = (int*)alloc((size_t)(N + 1) * 4);      // 0.4 MB
    int*  cur  = (int*)alloc((size_t)N * 4);            // 0.4 MB
    int*  deg  = (int*)alloc((size_t)N * 4);            // 0.4 MB
    int*  Pb   = (int*)alloc(4096 * 4);                 // 16 KB
    bf16* h1   = (bf16*)alloc((size_t)N * 128 * 2);     // 25.6 MB
    bf16* xbf  = (bf16*)alloc((size_t)N * 128 * 2);     // 25.6 MB (reused as h2)
    bf16* aggb = (bf16*)alloc((size_t)N * 128 * 2);     // 25.6 MB
    bf16* wsw1 = (bf16*)alloc(32768 * 2);               // 64 KB
    bf16* wsw2 = (bf16*)alloc(32768 * 2);
    bf16* wsw3 = (bf16*)alloc(32768 * 2);

    // ---- cooperative mega-kernel path ----
    static int maxGrid = 0;
    if (maxGrid == 0) {
        int perCU = 0, nCU = 0, dev = 0;
        hipError_t e1 = hipGetDevice(&dev);
        hipError_t e2 = hipDeviceGetAttribute(&nCU, hipDeviceAttributeMultiprocessorCount, dev);
        hipError_t e3 = hipOccupancyMaxActiveBlocksPerMultiprocessor(&perCU, mega_kernel, 256, 0);
        if (e1 == hipSuccess && e2 == hipSuccess && e3 == hipSuccess && perCU > 0 && nCU > 0)
            maxGrid = perCU * nCU;
        else
            maxGrid = -1;
    }

    if (maxGrid > 0) {
        const int grid = (maxGrid < 2048) ? maxGrid : 2048;
        MegaArgs ma;
        ma.x = x; ma.ei = ei;
        ma.wr1 = w_rel1; ma.wo1 = w_root1; ma.wr2 = w_rel2; ma.wo2 = w_root2;
        ma.wr3 = w_rel3; ma.wo3 = w_root3;
        ma.b1 = b1; ma.b2 = b2; ma.b3 = b3;
        ma.out = out;
        ma.xbf = xbf; ma.h1 = h1; ma.aggb = aggb;
        ma.wsw1 = wsw1; ma.wsw2 = wsw2; ma.wsw3 = wsw3;
        ma.col = col; ma.rp = rp; ma.cur = cur; ma.deg = deg; ma.Pb = Pb;
        ma.N = N; ma.E = E;
        void* args[] = {&ma};
        if (hipLaunchCooperativeKernel((const void*)mega_kernel, dim3(grid), dim3(256),
                                       args, 0, stream) == hipSuccess)
            return;
        // fall through to multi-kernel path on launch failure
    }

    // ---- fallback: round-2 multi-kernel path ----
    int* T    = (int*)h1;
    int* bsum = (int*)(h1 + 1024 * 1024);
    int* ebuf = (int*)aggb;

    const int NB = (N + BSZ - 1) / BSZ;
    const int GB = (E + CHUNK - 1) / CHUNK;
    const int nT = NB * GB;
    const int scanTBlocks = (nT + 255) / 256;

    const int aggBlocks  = (N + 7) / 8;
    const int gemmBlocks = (N + 63) / 64;
    const int cvtBlocks  = (N * 32 + 255) / 256;

    prep_kernel<<<cvtBlocks + 48, 256, 0, stream>>>(
        x, xbf, N * 32, cvtBlocks,
        w_rel1, w_root1, w_rel2, w_root2, w_rel3, w_root3,
        wsw1, wsw2, wsw3);

    bhist_kernel<<<GB, 256, 0, stream>>>(dst, T, E, NB, GB);
    scan1_kernel<<<scanTBlocks, 256, 0, stream>>>(T, T, bsum, nT);
    scan2_kernel<<<1, 512, 0, stream>>>(bsum, scanTBlocks);
    scan3_kernel<<<scanTBlocks, 256, 0, stream>>>(T, bsum, nT);
    bscatter_kernel<<<GB, 256, 0, stream>>>(src, dst, T, ebuf, E, NB, GB);
    bbuild_kernel<<<NB, 256, 0, stream>>>(T, ebuf, rp, col, E, N, NB, GB);

    agg_kernel<<<aggBlocks, 512, 0, stream>>>(xbf, rp, col, aggb, N);
    mfma_gemm_kernel<true, bf16><<<gemmBlocks, 256, 0, stream>>>(aggb, xbf, wsw1, b1, h1, N);
    agg_kernel<<<aggBlocks, 512, 0, stream>>>(h1, rp, col, aggb, N);
    mfma_gemm_kernel<true, bf16><<<gemmBlocks, 256, 0, stream>>>(aggb, h1, wsw2, b2, xbf, N);
    agg_kernel<<<aggBlocks, 512, 0, stream>>>(xbf, rp, col, aggb, N);
    mfma_gemm_kernel<false, float><<<gemmBlocks, 256, 0, stream>>>(aggb, xbf, wsw3, b3, out, N);
}

// Round 4
// 426.311 us; speedup vs baseline: 3.4265x; 3.4265x over previous
//
#include <hip/hip_runtime.h>
#include <hip/hip_bf16.h>
#include <stdint.h>

typedef __hip_bfloat16 bf16;
typedef __hip_bfloat162 bf162;

typedef __attribute__((ext_vector_type(8))) short short8;   // 8 bf16 = 4 VGPRs
typedef __attribute__((ext_vector_type(4))) float floatx4;  // MFMA accumulator

#define BSH   8        // bucket = 256 nodes
#define BSZ   256
#define CHUNK 8192     // edges per sort block
#define NBMAX 512      // max buckets supported (N <= 131072)

// ---------------- helpers ----------------

__device__ __forceinline__ void acc2(float& a, float& b, unsigned u) {
    a += __uint_as_float(u << 16);
    b += __uint_as_float(u & 0xffff0000u);
}

// ---------------- prep + bhist (single dispatch) ----------------
// blocks [0, nCvt):        x -> bf16
// blocks [nCvt, nCvt+48):  weights -> B-fragment layout for mfma_f32_16x16x32_bf16:
//   wsw[((kt*8+ct)*64+lane)*8 + j] = W[kt*32 + (lane>>4)*8 + j][ct*16 + (lane&15)]
//   where W = concat_k(w_rel, w_root), 256x128 row-major.
// blocks [nCvt+48, ...):   per-chunk bucket histogram of dst (independent of cvt/wsw)
__global__ __launch_bounds__(256)
void prep_bhist_kernel(const float* __restrict__ x, bf16* __restrict__ y, int n4, int nCvt,
                       const float* __restrict__ wr1, const float* __restrict__ wo1,
                       const float* __restrict__ wr2, const float* __restrict__ wo2,
                       const float* __restrict__ wr3, const float* __restrict__ wo3,
                       bf16* __restrict__ w1, bf16* __restrict__ w2, bf16* __restrict__ w3,
                       const int* __restrict__ dst, int* __restrict__ T,
                       int E, int NB, int GB) {
    __shared__ int lh[NBMAX];
    const int b = blockIdx.x;
    if (b < nCvt) {
        const int i = b * 256 + threadIdx.x;
        if (i < n4) {
            float4 v = ((const float4*)x)[i];
            bf162 a, c;
            a.x = __float2bfloat16(v.x); a.y = __float2bfloat16(v.y);
            c.x = __float2bfloat16(v.z); c.y = __float2bfloat16(v.w);
            ((bf162*)y)[i * 2]     = a;
            ((bf162*)y)[i * 2 + 1] = c;
        }
        return;
    }
    if (b < nCvt + 48) {
        int t = (b - nCvt) * 256 + threadIdx.x;       // 0..12287
        const int layer = t >> 12;
        t &= 4095;
        const float* wrel  = (layer == 0) ? wr1 : (layer == 1) ? wr2 : wr3;
        const float* wroot = (layer == 0) ? wo1 : (layer == 1) ? wo2 : wo3;
        bf16*        wsw   = (layer == 0) ? w1  : (layer == 1) ? w2  : w3;
        const int lane = t & 63;
        const int ct   = (t >> 6) & 7;
        const int kt   = t >> 9;
        const int kbase = kt * 32 + (lane >> 4) * 8;
        const int n     = ct * 16 + (lane & 15);
        bf16* q = wsw + (size_t)t * 8;
#pragma unroll
        for (int j = 0; j < 8; ++j) {
            const int k = kbase + j;
            const float v = (k < 128) ? wrel[k * 128 + n] : wroot[(k - 128) * 128 + n];
            q[j] = __float2bfloat16(v);
        }
        return;
    }
    // ---- bhist ----
    const int bb = b - nCvt - 48;
    for (int u = threadIdx.x; u < NB; u += 256) lh[u] = 0;
    __syncthreads();
    const int beg = bb * CHUNK, end = min(beg + CHUNK, E);
    for (int e = beg + threadIdx.x; e < end; e += 256)
        atomicAdd(&lh[dst[e] >> BSH], 1);
    __syncthreads();
    for (int u = threadIdx.x; u < NB; u += 256)
        T[u * GB + bb] = lh[u];
}

// ---------------- CSR build: two-level counting sort ----------------

__global__ __launch_bounds__(256)
void scan1_kernel(const int* __restrict__ deg, int* __restrict__ rp,
                  int* __restrict__ bsum, int n) {
    __shared__ int s[256];
    const int tid = threadIdx.x;
    const int i = blockIdx.x * 256 + tid;
    const int d = (i < n) ? deg[i] : 0;
    s[tid] = d;
    __syncthreads();
    for (int off = 1; off < 256; off <<= 1) {
        int u = (tid >= off) ? s[tid - off] : 0;
        __syncthreads();
        s[tid] += u;
        __syncthreads();
    }
    if (i < n) rp[i] = s[tid] - d;
    if (tid == 255) bsum[blockIdx.x] = s[255];
}

__global__ __launch_bounds__(512)
void scan2_kernel(int* __restrict__ bsum, int G) {
    __shared__ int s[512];
    const int tid = threadIdx.x;
    const int d = (tid < G) ? bsum[tid] : 0;
    s[tid] = d;
    __syncthreads();
    for (int off = 1; off < 512; off <<= 1) {
        int u = (tid >= off) ? s[tid - off] : 0;
        __syncthreads();
        s[tid] += u;
        __syncthreads();
    }
    if (tid < G) bsum[tid] = s[tid] - d;
}

// scan3 folded into the two consumers: Tfinal[i] = T[i] + bsum[i >> 8]

__global__ __launch_bounds__(256)
void bscatter_kernel(const int* __restrict__ src, const int* __restrict__ dst,
                     const int* __restrict__ T, const int* __restrict__ bsum,
                     int* __restrict__ ebuf, int E, int NB, int GB) {
    __shared__ int lofs[NBMAX];
    const int b = blockIdx.x;
    for (int u = threadIdx.x; u < NB; u += 256) {
        const int idx = u * GB + b;
        lofs[u] = T[idx] + bsum[idx >> 8];
    }
    __syncthreads();
    const int beg = b * CHUNK, end = min(beg + CHUNK, E);
    for (int e = beg + threadIdx.x; e < end; e += 256) {
        const int d = dst[e];
        const int u = d >> BSH;
        const int pos = atomicAdd(&lofs[u], 1);
        ebuf[pos] = (src[e] << BSH) | (d & (BSZ - 1));
    }
}

__global__ __launch_bounds__(256)
void bbuild_kernel(const int* __restrict__ T, const int* __restrict__ bsum,
                   const int* __restrict__ ebuf,
                   int* __restrict__ rp, int* __restrict__ col,
                   int E, int N, int NB, int GB) {
    __shared__ int s[256];
    __shared__ int lrank[256];
    const int u = blockIdx.x;
    const int tid = threadIdx.x;
    const int i0 = u * GB;
    const int beg = T[i0] + bsum[i0 >> 8];
    const int i1 = (u + 1) * GB;
    const int end = (u + 1 < NB) ? (T[i1] + bsum[i1 >> 8]) : E;

    lrank[tid] = 0;
    __syncthreads();
    for (int e = beg + tid; e < end; e += 256)
        atomicAdd(&lrank[ebuf[e] & (BSZ - 1)], 1);
    __syncthreads();
    const int cntv = lrank[tid];
    s[tid] = cntv;
    __syncthreads();
    for (int off = 1; off < 256; off <<= 1) {
        int v = (tid >= off) ? s[tid - off] : 0;
        __syncthreads();
        s[tid] += v;
        __syncthreads();
    }
    const int excl = s[tid] - cntv;
    const int node = u * BSZ + tid;
    if (node < N) rp[node] = beg + excl;
    if (u == NB - 1 && tid == 0) rp[N] = E;
    lrank[tid] = beg + excl;
    __syncthreads();
    for (int e = beg + tid; e < end; e += 256) {
        const int p = ebuf[e];
        const int pos = atomicAdd(&lrank[p & (BSZ - 1)], 1);
        col[pos] = p >> BSH;
    }
}

// ---------------- aggregation (CSR, atomic-free, bf16) ----------------
// PROVEN 64 us / 176 MB L2-fill (service-rate-bound) -- byte-identical to round-2.
// one wave per node; lanes 0-31 own features l32*4..+3 of even edges, lanes
// 32-63 of odd edges; dwordx2 per lane = 2 rows/instruction; shfl_xor(32) combine.

__global__ __launch_bounds__(512)
void agg_kernel(const bf16* __restrict__ h, const int* __restrict__ rp,
                const int* __restrict__ col, bf16* __restrict__ agg, int N) {
    const int lane = threadIdx.x & 63;
    const int wid  = threadIdx.x >> 6;
    const int node = blockIdx.x * 8 + wid;
    if (node >= N) return;
    const int half = lane >> 5;
    const int l32  = lane & 31;
    const int f    = l32 * 4;
    const int beg = rp[node], end = rp[node + 1];

    float acc[4] = {0.f, 0.f, 0.f, 0.f};
    int e = beg;
#pragma unroll 2
    for (; e + 8 <= end; e += 8) {
        const int s0 = col[e + half];
        const int s1 = col[e + 2 + half];
        const int s2 = col[e + 4 + half];
        const int s3 = col[e + 6 + half];
        const uint2 r0 = *(const uint2*)(h + (size_t)s0 * 128 + f);
        const uint2 r1 = *(const uint2*)(h + (size_t)s1 * 128 + f);
        const uint2 r2 = *(const uint2*)(h + (size_t)s2 * 128 + f);
        const uint2 r3 = *(const uint2*)(h + (size_t)s3 * 128 + f);
        acc2(acc[0], acc[1], r0.x); acc2(acc[2], acc[3], r0.y);
        acc2(acc[0], acc[1], r1.x); acc2(acc[2], acc[3], r1.y);
        acc2(acc[0], acc[1], r2.x); acc2(acc[2], acc[3], r2.y);
        acc2(acc[0], acc[1], r3.x); acc2(acc[2], acc[3], r3.y);
    }
    for (; e < end; e += 2) {
        const bool act = (e + half) < end;
        const int s = col[act ? (e + half) : e];
        const uint2 r = *(const uint2*)(h + (size_t)s * 128 + f);
        if (act) { acc2(acc[0], acc[1], r.x); acc2(acc[2], acc[3], r.y); }
    }
#pragma unroll
    for (int j = 0; j < 4; ++j)
        acc[j] += __shfl_xor(acc[j], 32, 64);
    if (half == 0) {
        bf162 o0, o1;
        o0.x = __float2bfloat16(acc[0]); o0.y = __float2bfloat16(acc[1]);
        o1.x = __float2bfloat16(acc[2]); o1.y = __float2bfloat16(acc[3]);
        bf162* q = (bf162*)(agg + (size_t)node * 128 + f);
        q[0] = o0;
        q[1] = o1;
    }
}

// ---------------- MFMA dual GEMM: out = [agg|h] @ Wsw + b (+relu) ----------------
// 512 threads, 128 rows/block. Changes vs round-2 (37 us each):
//  1. wsw (64 KB) staged ONCE into LDS per block -- kills the 400 MB of
//     per-wave global B-fragment re-reads (8 waves x 64 KB/block).
//  2. epilogue routed through an LDS tile (padded stride, ~2-way conflicts)
//     then written with coalesced dwordx4 -- kills the 32 scattered 2-byte
//     stores/thread (4x transaction inflation on 25.6 MB output).
// LDS 66 KB -> 2 blocks/CU, 16 waves/CU.

template <bool RELU, typename OT>
__global__ __launch_bounds__(512)
void mfma_gemm_kernel(const bf16* __restrict__ Aagg, const bf16* __restrict__ Hroot,
                      const bf16* __restrict__ wsw, const float* __restrict__ bias,
                      OT* __restrict__ out, int M) {
    __shared__ __align__(16) char smem[67584];
    const int tid = threadIdx.x;

    // stage all B-fragments (65536 B) into LDS: 512 thr x 16 B x 8
#pragma unroll
    for (int i = 0; i < 8; ++i) {
        const int off = i * 8192 + tid * 16;
        *(float4*)(smem + off) = *(const float4*)((const char*)wsw + off);
    }
    __syncthreads();

    const int lane = tid & 63;
    const int wave = tid >> 6;
    const int l15  = lane & 15;
    const int quad = lane >> 4;
    const int base = blockIdx.x * 128;
    const int row_a = base + wave * 16 + l15;
    const bool rowok = row_a < M;
    const bf16* wl = (const bf16*)smem;

    floatx4 acc[8];
#pragma unroll
    for (int ct = 0; ct < 8; ++ct) acc[ct] = (floatx4){0.f, 0.f, 0.f, 0.f};

#pragma unroll
    for (int kt = 0; kt < 8; ++kt) {
        const bf16* Abase = (kt < 4) ? Aagg : Hroot;
        const int k0 = (kt & 3) * 32 + quad * 8;
        short8 afrag = (short8){0, 0, 0, 0, 0, 0, 0, 0};
        if (rowok) afrag = *(const short8*)(Abase + (size_t)row_a * 128 + k0);
#pragma unroll
        for (int ct = 0; ct < 8; ++ct) {
            const short8 bfrag = *(const short8*)(wl + (size_t)((kt * 8 + ct) * 64 + lane) * 8);
            acc[ct] = __builtin_amdgcn_mfma_f32_16x16x32_bf16(afrag, bfrag, acc[ct], 0, 0, 0);
        }
    }

    __syncthreads();   // all waves done reading wl -> reuse smem as output tile
    const int rloc = wave * 16 + quad * 4;

    if constexpr (sizeof(OT) == 2) {
        bf16* tl = (bf16*)smem;                // stride 136 bf16 = 272 B (16-aligned)
#pragma unroll
        for (int ct = 0; ct < 8; ++ct) {
            const int colc = ct * 16 + l15;
            const float bv = bias[colc];
#pragma unroll
            for (int r = 0; r < 4; ++r) {
                float v = acc[ct][r] + bv;
                if (RELU) v = fmaxf(v, 0.f);
                tl[(rloc + r) * 136 + colc] = __float2bfloat16(v);
            }
        }
        __syncthreads();
        // 128 rows x 256 B out, coalesced dwordx4: 2048 chunks / 512 thr
#pragma unroll
        for (int i = 0; i < 4; ++i) {
            const int chunk = i * 512 + tid;
            const int row = chunk >> 4;
            const int c   = chunk & 15;
            if (base + row < M)
                *(float4*)((char*)out + (size_t)(base + row) * 256 + c * 16) =
                    *(const float4*)(smem + row * 272 + c * 16);
        }
    } else {
        float* tl = (float*)smem;              // stride 132 f32 = 528 B (16-aligned)
#pragma unroll
        for (int ct = 0; ct < 8; ++ct) {
            const int colc = ct * 16 + l15;
            const float bv = bias[colc];
#pragma unroll
            for (int r = 0; r < 4; ++r) {
                float v = acc[ct][r] + bv;
                if (RELU) v = fmaxf(v, 0.f);
                tl[(rloc + r) * 132 + colc] = v;
            }
        }
        __syncthreads();
        // 128 rows x 512 B out: 4096 chunks / 512 thr
#pragma unroll
        for (int i = 0; i < 8; ++i) {
            const int chunk = i * 512 + tid;
            const int row = chunk >> 5;
            const int c   = chunk & 31;
            if (base + row < M)
                *(float4*)((char*)out + (size_t)(base + row) * 512 + c * 16) =
                    *(const float4*)(smem + row * 528 + c * 16);
        }
    }
}

// ---------------- launch ----------------

extern "C" void kernel_launch(void* const* d_in, const int* in_sizes, int n_in,
                              void* d_out, int out_size, void* d_ws, size_t ws_size,
                              hipStream_t stream) {
    const float* x       = (const float*)d_in[0];
    const int*   ei      = (const int*)d_in[1];
    const float* w_rel1  = (const float*)d_in[2];
    const float* w_root1 = (const float*)d_in[3];
    const float* b1      = (const float*)d_in[4];
    const float* w_rel2  = (const float*)d_in[5];
    const float* w_root2 = (const float*)d_in[6];
    const float* b2      = (const float*)d_in[7];
    const float* w_rel3  = (const float*)d_in[8];
    const float* w_root3 = (const float*)d_in[9];
    const float* b3      = (const float*)d_in[10];
    float* out = (float*)d_out;

    const int N = in_sizes[0] / 128;
    const int E = in_sizes[1] / 2;
    const int* src = ei;
    const int* dst = ei + E;

    // workspace layout (~84 MB)
    char* w = (char*)d_ws;
    auto alloc = [&](size_t bytes) {
        char* p = w;
        w += (bytes + 255) & ~(size_t)255;
        return p;
    };
    int*  col  = (int*)alloc((size_t)E * 4);            // 6.4 MB
    int*  rp   = (int*)alloc((size_t)(N + 1) * 4);      // 0.4 MB
    bf16* h1   = (bf16*)alloc((size_t)N * 128 * 2);     // 25.6 MB
    bf16* xbf  = (bf16*)alloc((size_t)N * 128 * 2);     // 25.6 MB (reused as h2)
    bf16* aggb = (bf16*)alloc((size_t)N * 128 * 2);     // 25.6 MB
    bf16* wsw1 = (bf16*)alloc(32768 * 2);               // 64 KB
    bf16* wsw2 = (bf16*)alloc(32768 * 2);
    bf16* wsw3 = (bf16*)alloc(32768 * 2);
    bf16* h2   = xbf;       // layer-2 output overwrites xbf (last read: layer-1 gemm)
    // CSR-build scratch aliases buffers written only AFTER the build completes:
    int*  T    = (int*)h1;                  // NB*GB ints (~306 KB) in h1's space
    int*  bsum = (int*)(h1 + 1024 * 1024);  // scan partials, past T
    int*  ebuf = (int*)aggb;                // E ints (6.4 MB) in aggb's space

    const int NB = (N + BSZ - 1) / BSZ;        // 391 buckets
    const int GB = (E + CHUNK - 1) / CHUNK;    // 196 sort blocks
    const int nT = NB * GB;                    // 76,636
    const int scanTBlocks = (nT + 255) / 256;  // 300 <= 512

    const int aggBlocks  = (N + 7) / 8;
    const int gemmBlocks = (N + 127) / 128;
    const int cvtBlocks  = (N * 32 + 255) / 256;

    // prep (cvt + wsw) and bhist: independent work, one dispatch
    prep_bhist_kernel<<<cvtBlocks + 48 + GB, 256, 0, stream>>>(
        x, xbf, N * 32, cvtBlocks,
        w_rel1, w_root1, w_rel2, w_root2, w_rel3, w_root3,
        wsw1, wsw2, wsw3,
        dst, T, E, NB, GB);

    // CSR by dst: two-level counting sort (scan3 folded into consumers)
    scan1_kernel<<<scanTBlocks, 256, 0, stream>>>(T, T, bsum, nT);
    scan2_kernel<<<1, 512, 0, stream>>>(bsum, scanTBlocks);
    bscatter_kernel<<<GB, 256, 0, stream>>>(src, dst, T, bsum, ebuf, E, NB, GB);
    bbuild_kernel<<<NB, 256, 0, stream>>>(T, bsum, ebuf, rp, col, E, N, NB, GB);

    // layer 1
    agg_kernel<<<aggBlocks, 512, 0, stream>>>(xbf, rp, col, aggb, N);
    mfma_gemm_kernel<true, bf16><<<gemmBlocks, 512, 0, stream>>>(aggb, xbf, wsw1, b1, h1, N);
    // layer 2
    agg_kernel<<<aggBlocks, 512, 0, stream>>>(h1, rp, col, aggb, N);
    mfma_gemm_kernel<true, bf16><<<gemmBlocks, 512, 0, stream>>>(aggb, h1, wsw2, b2, h2, N);
    // layer 3
    agg_kernel<<<aggBlocks, 512, 0, stream>>>(h2, rp, col, aggb, N);
    mfma_gemm_kernel<false, float><<<gemmBlocks, 512, 0, stream>>>(aggb, h2, wsw3, b3, out, N);
}